// Round 2
// baseline (510.972 us; speedup 1.0000x reference)
//
#include <hip/hip_runtime.h>

// B=4096, P=10, LD=TD=512, DIN=2048, M1=B*P=40960, N1=512, K2=5120
typedef __attribute__((ext_vector_type(4))) float f32x4;
typedef __attribute__((ext_vector_type(8))) short short8;
typedef __attribute__((ext_vector_type(4))) short short4v;
typedef __attribute__((ext_vector_type(8))) unsigned short ushort8;

__device__ __forceinline__ unsigned short f2bf(float f) {
  unsigned u = __float_as_uint(f);
  u = (u + 0x7fffu + ((u >> 16) & 1u)) >> 16;  // RNE
  return (unsigned short)u;
}
__device__ __forceinline__ float bf2f(unsigned short h) {
  return __uint_as_float(((unsigned)h) << 16);
}

// W1 [2048][512] fp32 -> W1t2 bf16 tiled [kt=64][n=512][kk=32]
// Coalesced-read LDS transpose. grid = 64 kt * 4 n-quarters = 256 blocks.
__global__ __launch_bounds__(256) void prep_w1_k(const float* __restrict__ W1,
                                                 unsigned short* __restrict__ W1t2) {
  __shared__ short Lt[32][136];  // 32 k-rows x 128 n-cols (+8 pad)
  const int t = threadIdx.x;
  const int kt = blockIdx.x >> 2;
  const int nq = blockIdx.x & 3;
  // read phase: 32 rows x 128 cols fp32, coalesced f32x4
  #pragma unroll
  for (int p = 0; p < 4; ++p) {
    int idx = p * 256 + t;
    int row = idx >> 5;
    int c4 = idx & 31;
    f32x4 v = *(const f32x4*)&W1[(kt * 32 + row) * 512 + nq * 128 + c4 * 4];
    short4v w;
    #pragma unroll
    for (int i = 0; i < 4; ++i) w[i] = (short)f2bf(v[i]);
    *(short4v*)&Lt[row][c4 * 4] = w;
  }
  __syncthreads();
  // write phase: out[kt][n][kk], contiguous short8 per thread
  unsigned short* obase = W1t2 + kt * 16384 + nq * 4096;
  #pragma unroll
  for (int q = 0; q < 2; ++q) {
    int g = q * 2048 + t * 8;
    int n_l = g >> 5;
    int kk0 = g & 31;
    short8 s;
    #pragma unroll
    for (int j = 0; j < 8; ++j) s[j] = Lt[kk0 + j][n_l];
    *(short8*)&obase[g] = s;
  }
}

// W2 [5120][10] fp32 -> W2t bf16 [10][5120], read-coalesced
__global__ __launch_bounds__(256) void prep_w2_k(const float* __restrict__ W2,
                                                 unsigned short* __restrict__ W2t) {
  int f = blockIdx.x * 256 + threadIdx.x;       // 51,200 exact
  int k = f / 10;
  int j = f - k * 10;
  W2t[j * 5120 + k] = f2bf(W2[f]);
}

// emb[m][n] = relu(ctx[m][:] @ W1[:][n] + b1[n]), ctx = concat(agent, lane, nghl, nghc)
// block: 512 thr (8 waves), BM=64, BN=512 (full), BK=32, 16x16x32 bf16 MFMA.
// Barrier is lgkm-only (raw s_barrier) so global prefetches stay in flight.
__global__ __launch_bounds__(512, 4) void gemm1_k(
    const float* __restrict__ agent, const float* __restrict__ lanec,
    const float* __restrict__ nghl, const float* __restrict__ nghc,
    const unsigned short* __restrict__ W1t2, const float* __restrict__ b1,
    unsigned short* __restrict__ emb)
{
  __shared__ __align__(16) short Alds[2][64][40];   // +8 pad
  const int tid = threadIdx.x;
  const int wid = tid >> 6;        // 0..7 -> n-slice of 64
  const int lane = tid & 63;
  const int m0 = blockIdx.x * 64;

  const int srow = tid >> 3;
  const int scol = (tid & 7) << 2;
  const int mrow = m0 + srow;
  const int rowoff = mrow * 512 + scol;
  const int rowoff_a = (mrow / 10) * 512 + scol;

  const int fr = lane & 15;
  const int fk = (lane >> 4) << 3;

  const unsigned short* Bbase = W1t2 + (wid * 64 + fr) * 32 + fk;

  auto loadA = [&](int kt) -> f32x4 {
    int k0 = kt << 5;
    const float* p;
    if (k0 < 512)       p = agent + rowoff_a + k0;
    else if (k0 < 1024) p = lanec + rowoff + (k0 - 512);
    else if (k0 < 1536) p = nghl  + rowoff + (k0 - 1024);
    else                p = nghc  + rowoff + (k0 - 1536);
    return *(const f32x4*)p;
  };

  f32x4 acc[4][4];
  #pragma unroll
  for (int i = 0; i < 4; ++i)
    #pragma unroll
    for (int j = 0; j < 4; ++j) acc[i][j] = (f32x4)0.f;

  // prologue: stage tile 0; A-prefetch depth 3; B-prefetch depth 1
  {
    f32x4 v = loadA(0);
    short4v w;
    #pragma unroll
    for (int i = 0; i < 4; ++i) w[i] = (short)f2bf(v[i]);
    *(short4v*)&Alds[0][srow][scol] = w;
  }
  f32x4 pf0 = loadA(1);
  f32x4 pf1 = loadA(2);
  f32x4 pf2 = loadA(3);
  short8 bq[4];
  #pragma unroll
  for (int ni = 0; ni < 4; ++ni) bq[ni] = *(const short8*)(Bbase + ni * 512);

  int cur = 0;
  for (int kt = 0; kt < 64; ++kt) {
    // lgkm-only barrier: own ds_write + ds_reads drained, vmem stays in flight
    asm volatile("s_waitcnt lgkmcnt(0)\n\ts_barrier" ::: "memory");
    short8 af[4];
    #pragma unroll
    for (int mi = 0; mi < 4; ++mi)
      af[mi] = *(const short8*)&Alds[cur][mi * 16 + fr][fk];
    short8 bc[4];
    #pragma unroll
    for (int ni = 0; ni < 4; ++ni) bc[ni] = bq[ni];
    if (kt < 63) {
      const unsigned short* bp = Bbase + (kt + 1) * 16384;
      #pragma unroll
      for (int ni = 0; ni < 4; ++ni) bq[ni] = *(const short8*)(bp + ni * 512);
    }
    f32x4 wv = pf0;
    pf0 = pf1;
    pf1 = pf2;
    if (kt < 60) pf2 = loadA(kt + 4);
    #pragma unroll
    for (int mi = 0; mi < 4; ++mi)
      #pragma unroll
      for (int ni = 0; ni < 4; ++ni)
        acc[mi][ni] = __builtin_amdgcn_mfma_f32_16x16x32_bf16(af[mi], bc[ni], acc[mi][ni], 0, 0, 0);
    if (kt < 63) {
      short4v w;
      #pragma unroll
      for (int i = 0; i < 4; ++i) w[i] = (short)f2bf(wv[i]);
      *(short4v*)&Alds[cur ^ 1][srow][scol] = w;
    }
    cur ^= 1;
  }

  // epilogue: +b1, relu, bf16 store to ws
  float b1v[4];
  #pragma unroll
  for (int ni = 0; ni < 4; ++ni) b1v[ni] = b1[wid * 64 + ni * 16 + fr];
  const int r0 = (lane >> 4) << 2;
  #pragma unroll
  for (int mi = 0; mi < 4; ++mi) {
    #pragma unroll
    for (int r = 0; r < 4; ++r) {
      int m = m0 + mi * 16 + r0 + r;
      unsigned short* erow = emb + m * 512 + wid * 64 + fr;
      #pragma unroll
      for (int ni = 0; ni < 4; ++ni) {
        float v = acc[mi][ni][r] + b1v[ni];
        v = fmaxf(v, 0.f);
        erow[ni * 16] = f2bf(v);
      }
    }
  }
}

// logits[b][j] = emb_flat[b][:] . W2t[j][:] + b2[j]; one wave per b
__global__ __launch_bounds__(256) void logits_k(
    const unsigned short* __restrict__ emb, const unsigned short* __restrict__ W2t,
    const float* __restrict__ b2, float* __restrict__ out)
{
  int b = (blockIdx.x * 256 + threadIdx.x) >> 6;
  int lane = threadIdx.x & 63;
  float acc[10];
  #pragma unroll
  for (int j = 0; j < 10; ++j) acc[j] = 0.f;
  const unsigned short* erow = emb + b * 5120 + lane * 8;
  const unsigned short* wbase = W2t + lane * 8;
  #pragma unroll
  for (int i = 0; i < 10; ++i) {
    ushort8 ev = *(const ushort8*)(erow + i * 512);
    float ef[8];
    #pragma unroll
    for (int t = 0; t < 8; ++t) ef[t] = bf2f(ev[t]);
    #pragma unroll
    for (int j = 0; j < 10; ++j) {
      ushort8 wv = *(const ushort8*)(wbase + j * 5120 + i * 512);
      #pragma unroll
      for (int t = 0; t < 8; ++t) acc[j] = fmaf(ef[t], bf2f(wv[t]), acc[j]);
    }
  }
  #pragma unroll
  for (int j = 0; j < 10; ++j)
    #pragma unroll
    for (int m = 1; m < 64; m <<= 1) acc[j] += __shfl_xor(acc[j], m, 64);
  if (lane == 0) {
    #pragma unroll
    for (int j = 0; j < 10; ++j) out[b * 10 + j] = acc[j] + b2[j];
  }
}

// one-hot -> index, 4096 entries
__global__ __launch_bounds__(256) void idx_k(const int* __restrict__ label,
                                             int* __restrict__ idxbuf) {
  int b = blockIdx.x * 256 + threadIdx.x;
  if (b < 4096) {
    const int* lb = label + b * 10;
    int idx = 0;
    #pragma unroll
    for (int j = 9; j >= 0; --j) if (lb[j] == 1) idx = j;
    idxbuf[b] = idx;
  }
}

// gather best-lane rows (exact fp32 copies). out: [logits 40960][bl][bnl][bnc]
__global__ __launch_bounds__(256) void gather_k(
    const float* __restrict__ lanec, const float* __restrict__ nghl,
    const float* __restrict__ nghc, const int* __restrict__ idxbuf,
    float* __restrict__ out)
{
  int g = blockIdx.x * 256 + threadIdx.x;  // 0 .. 3*4096*128-1
  int t = g >> 19;                          // tensor select (524288 chunks each)
  int r = g & 524287;
  int b = r >> 7;
  int i = (r & 127) << 2;
  int idx = idxbuf[b];
  const float* src = (t == 0 ? lanec : (t == 1 ? nghl : nghc)) + (b * 10 + idx) * 512 + i;
  float* dst = out + (t == 0 ? 40960 : (t == 1 ? 2138112 : 4235264)) + b * 512 + i;
  *(f32x4*)dst = *(const f32x4*)src;
}

extern "C" void kernel_launch(void* const* d_in, const int* in_sizes, int n_in,
                              void* d_out, int out_size, void* d_ws, size_t ws_size,
                              hipStream_t stream) {
  const float* agent = (const float*)d_in[0];
  const float* lanec = (const float*)d_in[1];
  const float* nghl  = (const float*)d_in[2];
  const float* nghc  = (const float*)d_in[3];
  const int*   label = (const int*)d_in[4];
  const float* W1    = (const float*)d_in[5];
  const float* b1    = (const float*)d_in[6];
  const float* W2    = (const float*)d_in[7];
  const float* b2    = (const float*)d_in[8];
  float* out = (float*)d_out;

  // ws carve: emb bf16 [40960][512] = 41,943,040 B; W1t2 = 2,097,152 B; W2t = 102,400 B
  unsigned short* emb  = (unsigned short*)d_ws;
  unsigned short* W1t2 = (unsigned short*)((char*)d_ws + 41943040);
  unsigned short* W2t  = (unsigned short*)((char*)d_ws + 41943040 + 2097152);
  // idx aliases the emb region: written AFTER logits_k has consumed emb
  int* idxbuf = (int*)d_ws;

  prep_w1_k<<<256, 256, 0, stream>>>(W1, W1t2);
  prep_w2_k<<<200, 256, 0, stream>>>(W2, W2t);
  gemm1_k<<<640, 512, 0, stream>>>(agent, lanec, nghl, nghc, W1t2, b1, emb);
  logits_k<<<1024, 256, 0, stream>>>(emb, W2t, b2, out);
  idx_k<<<16, 256, 0, stream>>>(label, idxbuf);
  gather_k<<<6144, 256, 0, stream>>>(lanec, nghl, nghc, idxbuf, out);
}